// Round 5
// baseline (411.062 us; speedup 1.0000x reference)
//
#include <hip/hip_runtime.h>
#include <hip/hip_bf16.h>
#include <math.h>

namespace {
constexpr int EDIM  = 512;
constexpr int DDIM  = 1024;
constexpr int ADIM  = 128;
constexpr int FDIM  = 32;
constexpr int KW    = 31;
constexpr int BATCH = 128;
constexpr int TDIM  = 512;

constexpr int BM = 64;   // t-tile
constexpr int BK = 64;   // k-tile (8 K-iterations over E=512)

typedef __attribute__((ext_vector_type(8))) short short8;
typedef __attribute__((ext_vector_type(4))) float floatx4;

__device__ __forceinline__ float fast_tanh(float x) {
  x = fminf(9.0f, fmaxf(-9.0f, x));
  float e = __expf(2.0f * x);
  return (e - 1.0f) / (e + 1.0f);
}

__device__ __forceinline__ ushort2 pack_bf16(float x, float y) {
  union { __hip_bfloat162 h; ushort2 u; } cv;
  cv.h = __float22bfloat162_rn(make_float2(x, y));
  return cv.u;
}

__device__ __forceinline__ short8 pack8(float4 a, float4 b) {
  union { ushort2 u[4]; short8 v; } o;
  o.u[0] = pack_bf16(a.x, a.y); o.u[1] = pack_bf16(a.z, a.w);
  o.u[2] = pack_bf16(b.x, b.y); o.u[3] = pack_bf16(b.z, b.w);
  return o.v;
}

// dec_p[b,a] = sum_d dec[b,d] * Wdec[a,d]   grid (B, 4), 256 thr
__global__ __launch_bounds__(256)
void dec_proj_kernel(const float* __restrict__ dec,
                     const float* __restrict__ Wdec,
                     float* __restrict__ dec_p) {
  int b = blockIdx.x, az = blockIdx.y;
  int tid = threadIdx.x;
  int al = tid >> 3, seg = tid & 7;
  int a = az * 32 + al;
  const float* dv = dec + (size_t)b * DDIM;
  const float* wv = Wdec + (size_t)a * DDIM;
  float s = 0.f;
  #pragma unroll 8
  for (int it = 0; it < 32; ++it) {
    int d = it * 32 + seg * 4;
    float4 d4 = *(const float4*)(dv + d);
    float4 w4 = *(const float4*)(wv + d);
    s += d4.x * w4.x + d4.y * w4.y + d4.z * w4.z + d4.w * w4.w;
  }
  s += __shfl_xor(s, 1, 64);
  s += __shfl_xor(s, 2, 64);
  s += __shfl_xor(s, 4, 64);
  if (seg == 0) dec_p[b * ADIM + a] = s;
}

// ---------------- energies v5: fp32-direct, register-prefetched ------------
// Reads fp32 enc/Wenc straight from d_in (no bf16 pre-pass). Per K-iter each
// thread prefetches 12 float4 one tile ahead, converts to bf16 in-register,
// ds_write_b128 into the XOR-swizzled layout (chunk c of row r at position
// c^(r&7)) that the MFMA fragment reads expect. loc_p folds in as a final
// K=32 MFMA iteration (A=conv(prev_attn), B=Wloc).
__global__ __launch_bounds__(256, 3)
void energies_kernel(const float* __restrict__ enc,     // [B,T,E] fp32
                     const float* __restrict__ Wenc,    // [A,E] fp32
                     const float* __restrict__ pa,      // [B,T]
                     const float* __restrict__ convw,   // [F,1,K]
                     const float* __restrict__ Wloc,    // [A,F]
                     const float* __restrict__ We,      // [A]
                     const float* __restrict__ be,      // [1]
                     const float* __restrict__ dec_p,   // [B,A]
                     float* __restrict__ energies) {    // [B,T]
  __shared__ ushort As[BM * 64];      // 8 KB  (row stride 64 ushorts = 128 B)
  __shared__ ushort Bs[ADIM * 64];    // 16 KB
  __shared__ float pa_s[96];
  __shared__ float cw_s[FDIM * 33];
  __shared__ float epart[2 * BM];

  const int tid  = threadIdx.x;
  const int b    = blockIdx.y;
  const int t0   = blockIdx.x * BM;
  const int wave = tid >> 6, lane = tid & 63;
  const int wt = wave >> 1, wa = wave & 1;
  const int lc = lane & 15, lq = lane >> 4;
  const int sw = lc & 7;

  if (tid < 96) {
    int gt = t0 - 15 + tid;
    pa_s[tid] = (gt >= 0 && gt < TDIM) ? pa[b * TDIM + gt] : 0.0f;
  }
  for (int id = tid; id < FDIM * KW; id += 256)
    cw_s[(id / KW) * 33 + (id % KW)] = convw[id];

  // ---- chunk descriptors (chunk = 8 consecutive elements = 2 float4) ----
  const float* gA[2]; ushort* lA[2];
  #pragma unroll
  for (int r = 0; r < 2; ++r) {
    int ca = tid + 256 * r;
    int row = ca >> 3, c = ca & 7;
    gA[r] = enc + ((size_t)(b * TDIM + t0 + row)) * EDIM + c * 8;
    lA[r] = As + row * 64 + (c ^ (row & 7)) * 8;
  }
  const float* gB[4]; ushort* lB[4];
  #pragma unroll
  for (int r = 0; r < 4; ++r) {
    int cb = tid + 256 * r;
    int row = cb >> 3, c = cb & 7;
    gB[r] = Wenc + (size_t)row * EDIM + c * 8;
    lB[r] = Bs + row * 64 + (c ^ (row & 7)) * 8;
  }

  // prefetch tile 0
  float4 ra[2][2], rb[4][2];
  #pragma unroll
  for (int r = 0; r < 2; ++r) {
    ra[r][0] = *(const float4*)(gA[r]);
    ra[r][1] = *(const float4*)(gA[r] + 4);
    gA[r] += BK;
  }
  #pragma unroll
  for (int r = 0; r < 4; ++r) {
    rb[r][0] = *(const float4*)(gB[r]);
    rb[r][1] = *(const float4*)(gB[r] + 4);
    gB[r] += BK;
  }

  // wloc prefetch + cvt (staged into Bs at the loc iteration)
  short8 wl[2]; ushort* lWl[2];
  #pragma unroll
  for (int r = 0; r < 2; ++r) {
    int cw = tid + 256 * r;
    int row = cw >> 2, c = cw & 3;
    float4 w0 = *(const float4*)(Wloc + row * FDIM + c * 8);
    float4 w1 = *(const float4*)(Wloc + row * FDIM + c * 8 + 4);
    wl[r] = pack8(w0, w1);
    lWl[r] = Bs + row * 64 + (c ^ (row & 7)) * 8;
  }

  __syncthreads();   // pa_s / cw_s visible

  // location conv into registers (A-operand of the final loc MFMA)
  const int tl = tid >> 2, fg = tid & 3;
  short8 cvo;
  {
    float cv[8];
    #pragma unroll
    for (int n = 0; n < 8; ++n) {
      int f = fg * 8 + n;
      float s = 0.f;
      #pragma unroll
      for (int k = 0; k < KW; ++k) s += pa_s[tl + k] * cw_s[f * 33 + k];
      cv[n] = s;
    }
    cvo = pack8(make_float4(cv[0], cv[1], cv[2], cv[3]),
                make_float4(cv[4], cv[5], cv[6], cv[7]));
  }

  floatx4 acc[2][4];
  #pragma unroll
  for (int tt = 0; tt < 2; ++tt)
    #pragma unroll
    for (int aT = 0; aT < 4; ++aT)
      acc[tt][aT] = (floatx4){0.f, 0.f, 0.f, 0.f};

  for (int kt = 0; kt < 8; ++kt) {
    if (kt) __syncthreads();   // previous tile's MFMA readers done
    // cvt + store tile kt (regs were prefetched last iteration)
    #pragma unroll
    for (int r = 0; r < 2; ++r) *(short8*)lA[r] = pack8(ra[r][0], ra[r][1]);
    #pragma unroll
    for (int r = 0; r < 4; ++r) *(short8*)lB[r] = pack8(rb[r][0], rb[r][1]);
    __syncthreads();           // tile kt visible
    if (kt < 7) {              // prefetch tile kt+1 (lands during MFMA stage)
      #pragma unroll
      for (int r = 0; r < 2; ++r) {
        ra[r][0] = *(const float4*)(gA[r]);
        ra[r][1] = *(const float4*)(gA[r] + 4);
        gA[r] += BK;
      }
      #pragma unroll
      for (int r = 0; r < 4; ++r) {
        rb[r][0] = *(const float4*)(gB[r]);
        rb[r][1] = *(const float4*)(gB[r] + 4);
        gB[r] += BK;
      }
    }
    #pragma unroll
    for (int kk = 0; kk < 2; ++kk) {
      const int cco = ((kk * 4 + lq) ^ sw) * 8;
      short8 af[2], bf[4];
      #pragma unroll
      for (int tt = 0; tt < 2; ++tt)
        af[tt] = *(const short8*)&As[(wt * 32 + tt * 16 + lc) * 64 + cco];
      #pragma unroll
      for (int aT = 0; aT < 4; ++aT)
        bf[aT] = *(const short8*)&Bs[(wa * 64 + aT * 16 + lc) * 64 + cco];
      #pragma unroll
      for (int tt = 0; tt < 2; ++tt)
        #pragma unroll
        for (int aT = 0; aT < 4; ++aT)
          acc[tt][aT] = __builtin_amdgcn_mfma_f32_16x16x32_bf16(
              af[tt], bf[aT], acc[tt][aT], 0, 0, 0);
    }
  }
  __syncthreads();   // tile-7 readers done

  // loc iteration: A = conv(prev_attn) [64x32], B = Wloc [128x32], K=32
  *(short8*)&As[tl * 64 + (fg ^ (tl & 7)) * 8] = cvo;
  *(short8*)lWl[0] = wl[0];
  *(short8*)lWl[1] = wl[1];
  __syncthreads();
  {
    const int cco = (lq ^ sw) * 8;
    short8 af[2], bf[4];
    #pragma unroll
    for (int tt = 0; tt < 2; ++tt)
      af[tt] = *(const short8*)&As[(wt * 32 + tt * 16 + lc) * 64 + cco];
    #pragma unroll
    for (int aT = 0; aT < 4; ++aT)
      bf[aT] = *(const short8*)&Bs[(wa * 64 + aT * 16 + lc) * 64 + cco];
    #pragma unroll
    for (int tt = 0; tt < 2; ++tt)
      #pragma unroll
      for (int aT = 0; aT < 4; ++aT)
        acc[tt][aT] = __builtin_amdgcn_mfma_f32_16x16x32_bf16(
            af[tt], bf[aT], acc[tt][aT], 0, 0, 0);
  }

  // epilogue: e[t] = sum_a tanh(acc + dec_p[a]) * We[a]
  float dpv[4], wev[4];
  #pragma unroll
  for (int aT = 0; aT < 4; ++aT) {
    int a = wa * 64 + aT * 16 + lc;
    dpv[aT] = dec_p[b * ADIM + a];
    wev[aT] = We[a];
  }
  #pragma unroll
  for (int tt = 0; tt < 2; ++tt) {
    float es[4] = {0.f, 0.f, 0.f, 0.f};
    #pragma unroll
    for (int aT = 0; aT < 4; ++aT)
      #pragma unroll
      for (int i = 0; i < 4; ++i)
        es[i] += fast_tanh(acc[tt][aT][i] + dpv[aT]) * wev[aT];
    #pragma unroll
    for (int m = 1; m < 16; m <<= 1)
      #pragma unroll
      for (int i = 0; i < 4; ++i) es[i] += __shfl_xor(es[i], m, 64);
    if (lc == 0)
      #pragma unroll
      for (int i = 0; i < 4; ++i)
        epart[wa * 64 + wt * 32 + tt * 16 + lq * 4 + i] = es[i];
  }
  __syncthreads();
  if (tid < BM)
    energies[(size_t)b * TDIM + t0 + tid] = epart[tid] + epart[64 + tid] + be[0];
}

// ---- fused softmax + context: grid (2 e-chunks, B), 256 thr ---------------
// Each block redundantly computes softmax for its batch row (energies in ws,
// attn written to d_out by ex==0 only), keeps weights in LDS, then
// accumulates its 256-wide e-chunk over all T. No atomics, no memset.
__global__ __launch_bounds__(256)
void softmax_context_kernel(const float* __restrict__ enc,
                            const float* __restrict__ energ,
                            float* __restrict__ attn,
                            float* __restrict__ ctx) {
  __shared__ float aw[TDIM];
  __shared__ float redm[4];
  __shared__ float reds[4];
  const int b = blockIdx.y, ex = blockIdx.x, tid = threadIdx.x;
  const float* row = energ + (size_t)b * TDIM;
  float x0 = row[tid], x1 = row[tid + 256];
  float m = fmaxf(x0, x1);
  #pragma unroll
  for (int off = 32; off; off >>= 1) m = fmaxf(m, __shfl_xor(m, off, 64));
  int wid = tid >> 6, lane = tid & 63;
  if (lane == 0) redm[wid] = m;
  __syncthreads();
  m = fmaxf(fmaxf(redm[0], redm[1]), fmaxf(redm[2], redm[3]));
  float e0 = __expf(x0 - m), e1 = __expf(x1 - m);
  float s = e0 + e1;
  #pragma unroll
  for (int off = 32; off; off >>= 1) s += __shfl_xor(s, off, 64);
  if (lane == 0) reds[wid] = s;
  __syncthreads();
  s = reds[0] + reds[1] + reds[2] + reds[3];
  float inv = 1.0f / s;
  float w0 = e0 * inv, w1 = e1 * inv;
  aw[tid] = w0; aw[tid + 256] = w1;
  if (ex == 0) {
    attn[(size_t)b * TDIM + tid] = w0;
    attn[(size_t)b * TDIM + tid + 256] = w1;
  }
  __syncthreads();
  const int e = ex * 256 + tid;
  const float* ep = enc + ((size_t)b * TDIM) * EDIM + e;
  float acc = 0.f;
  #pragma unroll 16
  for (int t = 0; t < TDIM; ++t) acc += aw[t] * ep[(size_t)t * EDIM];
  ctx[(size_t)b * EDIM + e] = acc;
}

// In-place fallback (energies stored in attn slice): grid (1, B), each thread
// owns 2 e-columns; all reads of the energy row precede the in-place write by
// the same thread, so no cross-thread race.
__global__ __launch_bounds__(256)
void softmax_context_inplace_kernel(const float* __restrict__ enc,
                                    float* __restrict__ attn,
                                    float* __restrict__ ctx) {
  __shared__ float aw[TDIM];
  __shared__ float redm[4];
  __shared__ float reds[4];
  const int b = blockIdx.y, tid = threadIdx.x;
  float* row = attn + (size_t)b * TDIM;
  float x0 = row[tid], x1 = row[tid + 256];
  float m = fmaxf(x0, x1);
  #pragma unroll
  for (int off = 32; off; off >>= 1) m = fmaxf(m, __shfl_xor(m, off, 64));
  int wid = tid >> 6, lane = tid & 63;
  if (lane == 0) redm[wid] = m;
  __syncthreads();
  m = fmaxf(fmaxf(redm[0], redm[1]), fmaxf(redm[2], redm[3]));
  float e0 = __expf(x0 - m), e1 = __expf(x1 - m);
  float s = e0 + e1;
  #pragma unroll
  for (int off = 32; off; off >>= 1) s += __shfl_xor(s, off, 64);
  if (lane == 0) reds[wid] = s;
  __syncthreads();
  s = reds[0] + reds[1] + reds[2] + reds[3];
  float inv = 1.0f / s;
  float w0 = e0 * inv, w1 = e1 * inv;
  row[tid] = w0; row[tid + 256] = w1;
  aw[tid] = w0; aw[tid + 256] = w1;
  __syncthreads();
  const float* ep = enc + ((size_t)b * TDIM) * EDIM;
  float a0 = 0.f, a1 = 0.f;
  #pragma unroll 8
  for (int t = 0; t < TDIM; ++t) {
    float w = aw[t];
    a0 += w * ep[(size_t)t * EDIM + tid];
    a1 += w * ep[(size_t)t * EDIM + tid + 256];
  }
  ctx[(size_t)b * EDIM + tid] = a0;
  ctx[(size_t)b * EDIM + tid + 256] = a1;
}

}  // namespace

extern "C" void kernel_launch(void* const* d_in, const int* in_sizes, int n_in,
                              void* d_out, int out_size, void* d_ws, size_t ws_size,
                              hipStream_t stream) {
  const float* enc   = (const float*)d_in[0];
  const float* dec   = (const float*)d_in[1];
  const float* pa    = (const float*)d_in[2];
  const float* Wenc  = (const float*)d_in[3];
  const float* Wdec  = (const float*)d_in[4];
  const float* convw = (const float*)d_in[5];
  const float* Wloc  = (const float*)d_in[6];
  const float* We    = (const float*)d_in[7];
  const float* be    = (const float*)d_in[8];

  float* ctx  = (float*)d_out;                 // [B,E]
  float* attn = (float*)d_out + BATCH * EDIM;  // [B,T]

  float* dec_p = (float*)d_ws;                          // 64 KB
  float* energ = dec_p + BATCH * ADIM;                  // 256 KB

  const size_t need = (size_t)(BATCH * ADIM + BATCH * TDIM) * sizeof(float);

  dim3 g1(BATCH, 4);
  dec_proj_kernel<<<g1, 256, 0, stream>>>(dec, Wdec, dec_p);

  dim3 g2(TDIM / BM, BATCH);
  if (ws_size >= need) {
    energies_kernel<<<g2, 256, 0, stream>>>(enc, Wenc, pa, convw, Wloc, We, be,
                                            dec_p, energ);
    dim3 g3(2, BATCH);
    softmax_context_kernel<<<g3, 256, 0, stream>>>(enc, energ, attn, ctx);
  } else {
    energies_kernel<<<g2, 256, 0, stream>>>(enc, Wenc, pa, convw, Wloc, We, be,
                                            dec_p, attn);
    dim3 g3(1, BATCH);
    softmax_context_inplace_kernel<<<g3, 256, 0, stream>>>(enc, attn, ctx);
  }
}

// Round 6
// 283.291 us; speedup vs baseline: 1.4510x; 1.4510x over previous
//
#include <hip/hip_runtime.h>
#include <hip/hip_bf16.h>
#include <math.h>

namespace {
constexpr int EDIM  = 512;
constexpr int DDIM  = 1024;
constexpr int ADIM  = 128;
constexpr int FDIM  = 32;
constexpr int KW    = 31;
constexpr int BATCH = 128;
constexpr int TDIM  = 512;

constexpr int BM = 64;   // t-tile
constexpr int BK = 64;   // k-tile (8 K-iterations over E=512)

typedef __attribute__((ext_vector_type(8))) short short8;
typedef __attribute__((ext_vector_type(4))) float floatx4;

__device__ __forceinline__ float fast_tanh(float x) {
  x = fminf(9.0f, fmaxf(-9.0f, x));
  float e = __expf(2.0f * x);
  return (e - 1.0f) / (e + 1.0f);
}

__device__ __forceinline__ ushort2 pack_bf16(float x, float y) {
  union { __hip_bfloat162 h; ushort2 u; } cv;
  cv.h = __float22bfloat162_rn(make_float2(x, y));
  return cv.u;
}

__device__ __forceinline__ short8 pack8(floatx4 a, floatx4 b) {
  union { ushort2 u[4]; short8 v; } o;
  o.u[0] = pack_bf16(a[0], a[1]); o.u[1] = pack_bf16(a[2], a[3]);
  o.u[2] = pack_bf16(b[0], b[1]); o.u[3] = pack_bf16(b[2], b[3]);
  return o.v;
}

// dec_p[b,a] = sum_d dec[b,d] * Wdec[a,d]   grid (B, 4), 256 thr
__global__ __launch_bounds__(256)
void dec_proj_kernel(const float* __restrict__ dec,
                     const float* __restrict__ Wdec,
                     float* __restrict__ dec_p) {
  int b = blockIdx.x, az = blockIdx.y;
  int tid = threadIdx.x;
  int al = tid >> 3, seg = tid & 7;
  int a = az * 32 + al;
  const float* dv = dec + (size_t)b * DDIM;
  const float* wv = Wdec + (size_t)a * DDIM;
  float s = 0.f;
  #pragma unroll 8
  for (int it = 0; it < 32; ++it) {
    int d = it * 32 + seg * 4;
    float4 d4 = *(const float4*)(dv + d);
    float4 w4 = *(const float4*)(wv + d);
    s += d4.x * w4.x + d4.y * w4.y + d4.z * w4.z + d4.w * w4.w;
  }
  s += __shfl_xor(s, 1, 64);
  s += __shfl_xor(s, 2, 64);
  s += __shfl_xor(s, 4, 64);
  if (seg == 0) dec_p[b * ADIM + a] = s;
}

// ---------------- energies v6: fp32-direct, register-prefetched ------------
// v5 fix: NO min-waves launch bound (v5's (256,3) capped VGPR at 84 ->
// 344 MB of scratch spill, WRITE_SIZE 387 MB). enc reads are non-temporal
// so the 134 MB stream doesn't evict the 256 KB Wenc from per-XCD L2
// (v5 FETCH showed ~140 MB of Wenc re-fetch).
__global__ __launch_bounds__(256)
void energies_kernel(const float* __restrict__ enc,     // [B,T,E] fp32
                     const float* __restrict__ Wenc,    // [A,E] fp32
                     const float* __restrict__ pa,      // [B,T]
                     const float* __restrict__ convw,   // [F,1,K]
                     const float* __restrict__ Wloc,    // [A,F]
                     const float* __restrict__ We,      // [A]
                     const float* __restrict__ be,      // [1]
                     const float* __restrict__ dec_p,   // [B,A]
                     float* __restrict__ energies) {    // [B,T]
  __shared__ ushort As[BM * 64];      // 8 KB  (row stride 64 ushorts = 128 B)
  __shared__ ushort Bs[ADIM * 64];    // 16 KB
  __shared__ float pa_s[96];
  __shared__ float cw_s[FDIM * 33];
  __shared__ float epart[2 * BM];

  const int tid  = threadIdx.x;
  const int b    = blockIdx.y;
  const int t0   = blockIdx.x * BM;
  const int wave = tid >> 6, lane = tid & 63;
  const int wt = wave >> 1, wa = wave & 1;
  const int lc = lane & 15, lq = lane >> 4;
  const int sw = lc & 7;

  if (tid < 96) {
    int gt = t0 - 15 + tid;
    pa_s[tid] = (gt >= 0 && gt < TDIM) ? pa[b * TDIM + gt] : 0.0f;
  }
  for (int id = tid; id < FDIM * KW; id += 256)
    cw_s[(id / KW) * 33 + (id % KW)] = convw[id];

  // ---- chunk descriptors (chunk = 8 consecutive elements = 2 float4) ----
  const float* gA[2]; ushort* lA[2];
  #pragma unroll
  for (int r = 0; r < 2; ++r) {
    int ca = tid + 256 * r;
    int row = ca >> 3, c = ca & 7;
    gA[r] = enc + ((size_t)(b * TDIM + t0 + row)) * EDIM + c * 8;
    lA[r] = As + row * 64 + (c ^ (row & 7)) * 8;
  }
  const float* gB[4]; ushort* lB[4];
  #pragma unroll
  for (int r = 0; r < 4; ++r) {
    int cb = tid + 256 * r;
    int row = cb >> 3, c = cb & 7;
    gB[r] = Wenc + (size_t)row * EDIM + c * 8;
    lB[r] = Bs + row * 64 + (c ^ (row & 7)) * 8;
  }

  // prefetch tile 0 (enc non-temporal; Wenc cached)
  floatx4 ra[2][2], rb[4][2];
  #pragma unroll
  for (int r = 0; r < 2; ++r) {
    ra[r][0] = __builtin_nontemporal_load((const floatx4*)gA[r]);
    ra[r][1] = __builtin_nontemporal_load((const floatx4*)gA[r] + 1);
    gA[r] += BK;
  }
  #pragma unroll
  for (int r = 0; r < 4; ++r) {
    rb[r][0] = *(const floatx4*)(gB[r]);
    rb[r][1] = *(const floatx4*)(gB[r] + 4);
    gB[r] += BK;
  }

  // wloc prefetch + cvt (staged into Bs at the loc iteration)
  short8 wl[2]; ushort* lWl[2];
  #pragma unroll
  for (int r = 0; r < 2; ++r) {
    int cw = tid + 256 * r;
    int row = cw >> 2, c = cw & 3;
    floatx4 w0 = *(const floatx4*)(Wloc + row * FDIM + c * 8);
    floatx4 w1 = *(const floatx4*)(Wloc + row * FDIM + c * 8 + 4);
    wl[r] = pack8(w0, w1);
    lWl[r] = Bs + row * 64 + (c ^ (row & 7)) * 8;
  }

  __syncthreads();   // pa_s / cw_s visible

  // location conv into registers (A-operand of the final loc MFMA)
  const int tl = tid >> 2, fg = tid & 3;
  short8 cvo;
  {
    float cv[8];
    #pragma unroll
    for (int n = 0; n < 8; ++n) {
      int f = fg * 8 + n;
      float s = 0.f;
      #pragma unroll
      for (int k = 0; k < KW; ++k) s += pa_s[tl + k] * cw_s[f * 33 + k];
      cv[n] = s;
    }
    cvo = pack8((floatx4){cv[0], cv[1], cv[2], cv[3]},
                (floatx4){cv[4], cv[5], cv[6], cv[7]});
  }

  floatx4 acc[2][4];
  #pragma unroll
  for (int tt = 0; tt < 2; ++tt)
    #pragma unroll
    for (int aT = 0; aT < 4; ++aT)
      acc[tt][aT] = (floatx4){0.f, 0.f, 0.f, 0.f};

  for (int kt = 0; kt < 8; ++kt) {
    if (kt) __syncthreads();   // previous tile's MFMA readers done
    // cvt + store tile kt (regs were prefetched last iteration)
    #pragma unroll
    for (int r = 0; r < 2; ++r) *(short8*)lA[r] = pack8(ra[r][0], ra[r][1]);
    #pragma unroll
    for (int r = 0; r < 4; ++r) *(short8*)lB[r] = pack8(rb[r][0], rb[r][1]);
    __syncthreads();           // tile kt visible
    if (kt < 7) {              // prefetch tile kt+1 (lands during MFMA stage)
      #pragma unroll
      for (int r = 0; r < 2; ++r) {
        ra[r][0] = __builtin_nontemporal_load((const floatx4*)gA[r]);
        ra[r][1] = __builtin_nontemporal_load((const floatx4*)gA[r] + 1);
        gA[r] += BK;
      }
      #pragma unroll
      for (int r = 0; r < 4; ++r) {
        rb[r][0] = *(const floatx4*)(gB[r]);
        rb[r][1] = *(const floatx4*)(gB[r] + 4);
        gB[r] += BK;
      }
    }
    #pragma unroll
    for (int kk = 0; kk < 2; ++kk) {
      const int cco = ((kk * 4 + lq) ^ sw) * 8;
      short8 af[2], bf[4];
      #pragma unroll
      for (int tt = 0; tt < 2; ++tt)
        af[tt] = *(const short8*)&As[(wt * 32 + tt * 16 + lc) * 64 + cco];
      #pragma unroll
      for (int aT = 0; aT < 4; ++aT)
        bf[aT] = *(const short8*)&Bs[(wa * 64 + aT * 16 + lc) * 64 + cco];
      #pragma unroll
      for (int tt = 0; tt < 2; ++tt)
        #pragma unroll
        for (int aT = 0; aT < 4; ++aT)
          acc[tt][aT] = __builtin_amdgcn_mfma_f32_16x16x32_bf16(
              af[tt], bf[aT], acc[tt][aT], 0, 0, 0);
    }
  }
  __syncthreads();   // tile-7 readers done

  // loc iteration: A = conv(prev_attn) [64x32], B = Wloc [128x32], K=32
  *(short8*)&As[tl * 64 + (fg ^ (tl & 7)) * 8] = cvo;
  *(short8*)lWl[0] = wl[0];
  *(short8*)lWl[1] = wl[1];
  __syncthreads();
  {
    const int cco = (lq ^ sw) * 8;
    short8 af[2], bf[4];
    #pragma unroll
    for (int tt = 0; tt < 2; ++tt)
      af[tt] = *(const short8*)&As[(wt * 32 + tt * 16 + lc) * 64 + cco];
    #pragma unroll
    for (int aT = 0; aT < 4; ++aT)
      bf[aT] = *(const short8*)&Bs[(wa * 64 + aT * 16 + lc) * 64 + cco];
    #pragma unroll
    for (int tt = 0; tt < 2; ++tt)
      #pragma unroll
      for (int aT = 0; aT < 4; ++aT)
        acc[tt][aT] = __builtin_amdgcn_mfma_f32_16x16x32_bf16(
            af[tt], bf[aT], acc[tt][aT], 0, 0, 0);
  }

  // epilogue: e[t] = sum_a tanh(acc + dec_p[a]) * We[a]
  float dpv[4], wev[4];
  #pragma unroll
  for (int aT = 0; aT < 4; ++aT) {
    int a = wa * 64 + aT * 16 + lc;
    dpv[aT] = dec_p[b * ADIM + a];
    wev[aT] = We[a];
  }
  #pragma unroll
  for (int tt = 0; tt < 2; ++tt) {
    float es[4] = {0.f, 0.f, 0.f, 0.f};
    #pragma unroll
    for (int aT = 0; aT < 4; ++aT)
      #pragma unroll
      for (int i = 0; i < 4; ++i)
        es[i] += fast_tanh(acc[tt][aT][i] + dpv[aT]) * wev[aT];
    #pragma unroll
    for (int m = 1; m < 16; m <<= 1)
      #pragma unroll
      for (int i = 0; i < 4; ++i) es[i] += __shfl_xor(es[i], m, 64);
    if (lc == 0)
      #pragma unroll
      for (int i = 0; i < 4; ++i)
        epart[wa * 64 + wt * 32 + tt * 16 + lq * 4 + i] = es[i];
  }
  __syncthreads();
  if (tid < BM)
    energies[(size_t)b * TDIM + t0 + tid] = epart[tid] + epart[64 + tid] + be[0];
}

// ---- fused softmax + context: grid (2 e-chunks, B), 256 thr ---------------
__global__ __launch_bounds__(256)
void softmax_context_kernel(const float* __restrict__ enc,
                            const float* __restrict__ energ,
                            float* __restrict__ attn,
                            float* __restrict__ ctx) {
  __shared__ float aw[TDIM];
  __shared__ float redm[4];
  __shared__ float reds[4];
  const int b = blockIdx.y, ex = blockIdx.x, tid = threadIdx.x;
  const float* row = energ + (size_t)b * TDIM;
  float x0 = row[tid], x1 = row[tid + 256];
  float m = fmaxf(x0, x1);
  #pragma unroll
  for (int off = 32; off; off >>= 1) m = fmaxf(m, __shfl_xor(m, off, 64));
  int wid = tid >> 6, lane = tid & 63;
  if (lane == 0) redm[wid] = m;
  __syncthreads();
  m = fmaxf(fmaxf(redm[0], redm[1]), fmaxf(redm[2], redm[3]));
  float e0 = __expf(x0 - m), e1 = __expf(x1 - m);
  float s = e0 + e1;
  #pragma unroll
  for (int off = 32; off; off >>= 1) s += __shfl_xor(s, off, 64);
  if (lane == 0) reds[wid] = s;
  __syncthreads();
  s = reds[0] + reds[1] + reds[2] + reds[3];
  float inv = 1.0f / s;
  float w0 = e0 * inv, w1 = e1 * inv;
  aw[tid] = w0; aw[tid + 256] = w1;
  if (ex == 0) {
    attn[(size_t)b * TDIM + tid] = w0;
    attn[(size_t)b * TDIM + tid + 256] = w1;
  }
  __syncthreads();
  const int e = ex * 256 + tid;
  const float* ep = enc + ((size_t)b * TDIM) * EDIM + e;
  float acc = 0.f;
  #pragma unroll 16
  for (int t = 0; t < TDIM; ++t) acc += aw[t] * ep[(size_t)t * EDIM];
  ctx[(size_t)b * EDIM + e] = acc;
}

// In-place fallback (energies stored in attn slice)
__global__ __launch_bounds__(256)
void softmax_context_inplace_kernel(const float* __restrict__ enc,
                                    float* __restrict__ attn,
                                    float* __restrict__ ctx) {
  __shared__ float aw[TDIM];
  __shared__ float redm[4];
  __shared__ float reds[4];
  const int b = blockIdx.y, tid = threadIdx.x;
  float* row = attn + (size_t)b * TDIM;
  float x0 = row[tid], x1 = row[tid + 256];
  float m = fmaxf(x0, x1);
  #pragma unroll
  for (int off = 32; off; off >>= 1) m = fmaxf(m, __shfl_xor(m, off, 64));
  int wid = tid >> 6, lane = tid & 63;
  if (lane == 0) redm[wid] = m;
  __syncthreads();
  m = fmaxf(fmaxf(redm[0], redm[1]), fmaxf(redm[2], redm[3]));
  float e0 = __expf(x0 - m), e1 = __expf(x1 - m);
  float s = e0 + e1;
  #pragma unroll
  for (int off = 32; off; off >>= 1) s += __shfl_xor(s, off, 64);
  if (lane == 0) reds[wid] = s;
  __syncthreads();
  s = reds[0] + reds[1] + reds[2] + reds[3];
  float inv = 1.0f / s;
  float w0 = e0 * inv, w1 = e1 * inv;
  row[tid] = w0; row[tid + 256] = w1;
  aw[tid] = w0; aw[tid + 256] = w1;
  __syncthreads();
  const float* ep = enc + ((size_t)b * TDIM) * EDIM;
  float a0 = 0.f, a1 = 0.f;
  #pragma unroll 8
  for (int t = 0; t < TDIM; ++t) {
    float w = aw[t];
    a0 += w * ep[(size_t)t * EDIM + tid];
    a1 += w * ep[(size_t)t * EDIM + tid + 256];
  }
  ctx[(size_t)b * EDIM + tid] = a0;
  ctx[(size_t)b * EDIM + tid + 256] = a1;
}

}  // namespace

extern "C" void kernel_launch(void* const* d_in, const int* in_sizes, int n_in,
                              void* d_out, int out_size, void* d_ws, size_t ws_size,
                              hipStream_t stream) {
  const float* enc   = (const float*)d_in[0];
  const float* dec   = (const float*)d_in[1];
  const float* pa    = (const float*)d_in[2];
  const float* Wenc  = (const float*)d_in[3];
  const float* Wdec  = (const float*)d_in[4];
  const float* convw = (const float*)d_in[5];
  const float* Wloc  = (const float*)d_in[6];
  const float* We    = (const float*)d_in[7];
  const float* be    = (const float*)d_in[8];

  float* ctx  = (float*)d_out;                 // [B,E]
  float* attn = (float*)d_out + BATCH * EDIM;  // [B,T]

  float* dec_p = (float*)d_ws;                          // 64 KB
  float* energ = dec_p + BATCH * ADIM;                  // 256 KB

  const size_t need = (size_t)(BATCH * ADIM + BATCH * TDIM) * sizeof(float);

  dim3 g1(BATCH, 4);
  dec_proj_kernel<<<g1, 256, 0, stream>>>(dec, Wdec, dec_p);

  dim3 g2(TDIM / BM, BATCH);
  if (ws_size >= need) {
    energies_kernel<<<g2, 256, 0, stream>>>(enc, Wenc, pa, convw, Wloc, We, be,
                                            dec_p, energ);
    dim3 g3(2, BATCH);
    softmax_context_kernel<<<g3, 256, 0, stream>>>(enc, energ, attn, ctx);
  } else {
    energies_kernel<<<g2, 256, 0, stream>>>(enc, Wenc, pa, convw, Wloc, We, be,
                                            dec_p, attn);
    dim3 g3(1, BATCH);
    softmax_context_inplace_kernel<<<g3, 256, 0, stream>>>(enc, attn, ctx);
  }
}

// Round 7
// 260.760 us; speedup vs baseline: 1.5764x; 1.0864x over previous
//
#include <hip/hip_runtime.h>
#include <hip/hip_bf16.h>
#include <math.h>

namespace {
constexpr int EDIM  = 512;
constexpr int DDIM  = 1024;
constexpr int ADIM  = 128;
constexpr int FDIM  = 32;
constexpr int KW    = 31;
constexpr int BATCH = 128;
constexpr int TDIM  = 512;

typedef __attribute__((ext_vector_type(8))) short short8;
typedef __attribute__((ext_vector_type(4))) float floatx4;

__device__ __forceinline__ float fast_tanh(float x) {
  x = fminf(9.0f, fmaxf(-9.0f, x));
  float e = __expf(2.0f * x);
  return (e - 1.0f) / (e + 1.0f);
}

__device__ __forceinline__ ushort2 pack_bf16(float x, float y) {
  union { __hip_bfloat162 h; ushort2 u; } cv;
  cv.h = __float22bfloat162_rn(make_float2(x, y));
  return cv.u;
}

__device__ __forceinline__ short8 pack8(floatx4 a, floatx4 b) {
  union { ushort2 u[4]; short8 v; } o;
  o.u[0] = pack_bf16(a[0], a[1]); o.u[1] = pack_bf16(a[2], a[3]);
  o.u[2] = pack_bf16(b[0], b[1]); o.u[3] = pack_bf16(b[2], b[3]);
  return o.v;
}

// dec_p[b,a] = sum_d dec[b,d] * Wdec[a,d]   grid (B, 4), 256 thr
__global__ __launch_bounds__(256)
void dec_proj_kernel(const float* __restrict__ dec,
                     const float* __restrict__ Wdec,
                     float* __restrict__ dec_p) {
  int b = blockIdx.x, az = blockIdx.y;
  int tid = threadIdx.x;
  int al = tid >> 3, seg = tid & 7;
  int a = az * 32 + al;
  const float* dv = dec + (size_t)b * DDIM;
  const float* wv = Wdec + (size_t)a * DDIM;
  float s = 0.f;
  #pragma unroll 8
  for (int it = 0; it < 32; ++it) {
    int d = it * 32 + seg * 4;
    float4 d4 = *(const float4*)(dv + d);
    float4 w4 = *(const float4*)(wv + d);
    s += d4.x * w4.x + d4.y * w4.y + d4.z * w4.z + d4.w * w4.w;
  }
  s += __shfl_xor(s, 1, 64);
  s += __shfl_xor(s, 2, 64);
  s += __shfl_xor(s, 4, 64);
  if (seg == 0) dec_p[b * ADIM + a] = s;
}

// ---------------- energies v7: A-from-global, K-phased B, strip-pairs ------
// Block = (t-chunk of 128 rows, b). 4 waves; wave w owns strips {2w, 2w+1}
// (16 rows each) and all 128 a's. enc A-fragments are built directly from
// global (no LDS, no barrier), depth-1 register prefetch. Wenc staged in 4
// K-quarters (32 KB LDS, R6's verified zero-conflict chunk-XOR layout) ->
// only 10 barriers/block with >=64 MFMA per barrier interval. loc_p = final
// MFMA round: A = conv tile (LDS, computed once), B = Wloc (global, L1-hot).
__global__ __launch_bounds__(256)
void energies_kernel(const float* __restrict__ enc,     // [B,T,E] fp32
                     const float* __restrict__ Wenc,    // [A,E] fp32
                     const float* __restrict__ pa,      // [B,T]
                     const float* __restrict__ convw,   // [F,1,K]
                     const float* __restrict__ Wloc,    // [A,F]
                     const float* __restrict__ We,      // [A]
                     const float* __restrict__ be,      // [1]
                     const float* __restrict__ dec_p,   // [B,A]
                     float* __restrict__ energ) {       // [B,T]
  __shared__ ushort WencS[16384];   // 32 KB: [sup(2)][row(128)][chunk(8)*8]
  __shared__ ushort convS[4096];    // 8 KB:  [t_local(128)][f(32)]
  __shared__ float pa_s[160];
  __shared__ float cw_s[FDIM * 33];

  const int tid  = threadIdx.x;
  const int b    = blockIdx.y;
  const int t0b  = blockIdx.x * 128;
  const int wave = tid >> 6, lane = tid & 63;
  const int lc = lane & 15, lq = lane >> 4;
  const int sw = lc & 7;

  if (tid < 158) {
    int gt = t0b - 15 + tid;
    pa_s[tid] = (gt >= 0 && gt < TDIM) ? pa[b * TDIM + gt] : 0.f;
  }
  for (int id = tid; id < FDIM * KW; id += 256)
    cw_s[(id / KW) * 33 + (id % KW)] = convw[id];
  __syncthreads();

  // conv(prev_attn) once per block: thread -> (t_local = tid>>1, f-half)
  {
    const int tl = tid >> 1, fh = (tid & 1) * 16;
    float cv[16];
    #pragma unroll
    for (int n = 0; n < 16; ++n) {
      float s = 0.f;
      #pragma unroll
      for (int k = 0; k < KW; ++k) s += pa_s[tl + k] * cw_s[(fh + n) * 33 + k];
      cv[n] = s;
    }
    union { ushort2 u[8]; short8 v[2]; } o;
    #pragma unroll
    for (int n = 0; n < 8; ++n) o.u[n] = pack_bf16(cv[2 * n], cv[2 * n + 1]);
    *(short8*)&convS[tl * 32 + fh] = o.v[0];
    *(short8*)&convS[tl * 32 + fh + 8] = o.v[1];
  }

  // stage Wenc K-quarter 0 (2 super-tiles of BK=64; chunk c at pos c^(row&7))
  #pragma unroll
  for (int r = 0; r < 8; ++r) {
    int idx = tid + r * 256;
    int sup = idx >> 10, i2 = idx & 1023;
    int row = i2 >> 3, gc = (i2 & 7) ^ (row & 7);
    const float* g = Wenc + (size_t)row * EDIM + sup * 64 + gc * 8;
    *(short8*)&WencS[sup * 8192 + i2 * 8] =
        pack8(*(const floatx4*)g, *(const floatx4*)(g + 4));
  }

  // A-stream pointers + prefetch step 0 (strip0 = wave*2, strip1 = wave*2+1)
  const float* pA0 = enc + ((size_t)(b * TDIM + t0b + wave * 32 + lc)) * EDIM + lq * 8;
  const float* pA1 = pA0 + 16 * EDIM;
  floatx4 c0a = *(const floatx4*)pA0, c0b = *(const floatx4*)(pA0 + 4);
  floatx4 c1a = *(const floatx4*)pA1, c1b = *(const floatx4*)(pA1 + 4);

  float dpv[8], wev[8];
  #pragma unroll
  for (int aT = 0; aT < 8; ++aT) {
    int a = aT * 16 + lc;
    dpv[aT] = dec_p[b * ADIM + a];
    wev[aT] = We[a];
  }

  floatx4 acc0[8], acc1[8];
  #pragma unroll
  for (int aT = 0; aT < 8; ++aT) {
    acc0[aT] = (floatx4){0.f, 0.f, 0.f, 0.f};
    acc1[aT] = (floatx4){0.f, 0.f, 0.f, 0.f};
  }

  __syncthreads();   // convS + WencS(quarter 0) visible

  for (int ph = 0; ph < 4; ++ph) {
    if (ph) {
      __syncthreads();   // quarter ph-1 readers done
      #pragma unroll
      for (int r = 0; r < 8; ++r) {
        int idx = tid + r * 256;
        int sup = idx >> 10, i2 = idx & 1023;
        int row = i2 >> 3, gc = (i2 & 7) ^ (row & 7);
        const float* g = Wenc + (size_t)row * EDIM + ph * 128 + sup * 64 + gc * 8;
        *(short8*)&WencS[sup * 8192 + i2 * 8] =
            pack8(*(const floatx4*)g, *(const floatx4*)(g + 4));
      }
      __syncthreads();   // quarter ph visible
    }
    #pragma unroll
    for (int st = 0; st < 4; ++st) {
      const int step = ph * 4 + st;
      floatx4 n0a = {0,0,0,0}, n0b = {0,0,0,0}, n1a = {0,0,0,0}, n1b = {0,0,0,0};
      if (step < 15) {
        const float* q0 = pA0 + (step + 1) * 32;
        const float* q1 = pA1 + (step + 1) * 32;
        n0a = *(const floatx4*)q0; n0b = *(const floatx4*)(q0 + 4);
        n1a = *(const floatx4*)q1; n1b = *(const floatx4*)(q1 + 4);
      }
      short8 af0 = pack8(c0a, c0b);
      short8 af1 = pack8(c1a, c1b);
      const int cco = (((st & 1) * 4 + lq) ^ sw) * 8;
      const ushort* Bb = &WencS[(st >> 1) * 8192 + cco];
      #pragma unroll
      for (int aT = 0; aT < 8; ++aT) {
        short8 bf = *(const short8*)&Bb[(aT * 16 + lc) * 64];
        acc0[aT] = __builtin_amdgcn_mfma_f32_16x16x32_bf16(af0, bf, acc0[aT], 0, 0, 0);
        acc1[aT] = __builtin_amdgcn_mfma_f32_16x16x32_bf16(af1, bf, acc1[aT], 0, 0, 0);
      }
      c0a = n0a; c0b = n0b; c1a = n1a; c1b = n1b;
    }
  }

  // loc round: A = conv tile (convS), B = Wloc from global (L1-hot), K=32
  {
    short8 afl0 = *(const short8*)&convS[(wave * 32 + lc) * 32 + lq * 8];
    short8 afl1 = *(const short8*)&convS[(wave * 32 + 16 + lc) * 32 + lq * 8];
    #pragma unroll
    for (int aT = 0; aT < 8; ++aT) {
      const float* g = Wloc + (size_t)(aT * 16 + lc) * FDIM + lq * 8;
      short8 bfl = pack8(*(const floatx4*)g, *(const floatx4*)(g + 4));
      acc0[aT] = __builtin_amdgcn_mfma_f32_16x16x32_bf16(afl0, bfl, acc0[aT], 0, 0, 0);
      acc1[aT] = __builtin_amdgcn_mfma_f32_16x16x32_bf16(afl1, bfl, acc1[aT], 0, 0, 0);
    }
  }

  // epilogue (within-wave, no barriers): e[t] = sum_a tanh(x + dp)*We + be
  const float be0 = be[0];
  #pragma unroll
  for (int s = 0; s < 2; ++s) {
    float es[4] = {0.f, 0.f, 0.f, 0.f};
    #pragma unroll
    for (int aT = 0; aT < 8; ++aT) {
      const floatx4 av = s ? acc1[aT] : acc0[aT];
      #pragma unroll
      for (int i = 0; i < 4; ++i)
        es[i] += fast_tanh(av[i] + dpv[aT]) * wev[aT];
    }
    #pragma unroll
    for (int m = 1; m < 16; m <<= 1)
      #pragma unroll
      for (int i = 0; i < 4; ++i) es[i] += __shfl_xor(es[i], m, 64);
    if (lc == 0) {
      floatx4 ev = {es[0] + be0, es[1] + be0, es[2] + be0, es[3] + be0};
      *(floatx4*)&energ[(size_t)b * TDIM + t0b + wave * 32 + s * 16 + lq * 4] = ev;
    }
  }
}

// ---- fused softmax + context v2: grid (4 e-chunks of 128, B), 256 thr -----
// Redundant per-block softmax (energ in ws); thread = (col j, t-half h).
__global__ __launch_bounds__(256)
void softmax_context_kernel(const float* __restrict__ enc,
                            const float* __restrict__ energ,
                            float* __restrict__ attn,
                            float* __restrict__ ctx) {
  __shared__ float aw[TDIM];
  __shared__ float redm[4];
  __shared__ float reds[4];
  __shared__ float red2[128];
  const int b = blockIdx.y, ex = blockIdx.x, tid = threadIdx.x;
  const float* row = energ + (size_t)b * TDIM;
  float x0 = row[tid], x1 = row[tid + 256];
  float m = fmaxf(x0, x1);
  #pragma unroll
  for (int off = 32; off; off >>= 1) m = fmaxf(m, __shfl_xor(m, off, 64));
  int wid = tid >> 6, lane = tid & 63;
  if (lane == 0) redm[wid] = m;
  __syncthreads();
  m = fmaxf(fmaxf(redm[0], redm[1]), fmaxf(redm[2], redm[3]));
  float e0 = __expf(x0 - m), e1 = __expf(x1 - m);
  float s = e0 + e1;
  #pragma unroll
  for (int off = 32; off; off >>= 1) s += __shfl_xor(s, off, 64);
  if (lane == 0) reds[wid] = s;
  __syncthreads();
  s = reds[0] + reds[1] + reds[2] + reds[3];
  float inv = 1.0f / s;
  float w0 = e0 * inv, w1 = e1 * inv;
  aw[tid] = w0; aw[tid + 256] = w1;
  if (ex == 0) {
    attn[(size_t)b * TDIM + tid] = w0;
    attn[(size_t)b * TDIM + tid + 256] = w1;
  }
  __syncthreads();
  const int j = tid & 127, h = tid >> 7;
  const float* ep = enc + ((size_t)(b * TDIM + h * 256)) * EDIM + ex * 128 + j;
  float acc = 0.f;
  #pragma unroll 16
  for (int t = 0; t < 256; ++t) acc += aw[h * 256 + t] * ep[(size_t)t * EDIM];
  if (h == 1) red2[j] = acc;
  __syncthreads();
  if (h == 0) ctx[(size_t)b * EDIM + ex * 128 + j] = acc + red2[j];
}

// In-place fallback (energies stored in attn slice): grid (1, B)
__global__ __launch_bounds__(256)
void softmax_context_inplace_kernel(const float* __restrict__ enc,
                                    float* __restrict__ attn,
                                    float* __restrict__ ctx) {
  __shared__ float aw[TDIM];
  __shared__ float redm[4];
  __shared__ float reds[4];
  const int b = blockIdx.y, tid = threadIdx.x;
  float* row = attn + (size_t)b * TDIM;
  float x0 = row[tid], x1 = row[tid + 256];
  float m = fmaxf(x0, x1);
  #pragma unroll
  for (int off = 32; off; off >>= 1) m = fmaxf(m, __shfl_xor(m, off, 64));
  int wid = tid >> 6, lane = tid & 63;
  if (lane == 0) redm[wid] = m;
  __syncthreads();
  m = fmaxf(fmaxf(redm[0], redm[1]), fmaxf(redm[2], redm[3]));
  float e0 = __expf(x0 - m), e1 = __expf(x1 - m);
  float s = e0 + e1;
  #pragma unroll
  for (int off = 32; off; off >>= 1) s += __shfl_xor(s, off, 64);
  if (lane == 0) reds[wid] = s;
  __syncthreads();
  s = reds[0] + reds[1] + reds[2] + reds[3];
  float inv = 1.0f / s;
  float w0 = e0 * inv, w1 = e1 * inv;
  row[tid] = w0; row[tid + 256] = w1;
  aw[tid] = w0; aw[tid + 256] = w1;
  __syncthreads();
  const float* ep = enc + ((size_t)b * TDIM) * EDIM;
  float a0 = 0.f, a1 = 0.f;
  #pragma unroll 8
  for (int t = 0; t < TDIM; ++t) {
    float w = aw[t];
    a0 += w * ep[(size_t)t * EDIM + tid];
    a1 += w * ep[(size_t)t * EDIM + tid + 256];
  }
  ctx[(size_t)b * EDIM + tid] = a0;
  ctx[(size_t)b * EDIM + tid + 256] = a1;
}

}  // namespace

extern "C" void kernel_launch(void* const* d_in, const int* in_sizes, int n_in,
                              void* d_out, int out_size, void* d_ws, size_t ws_size,
                              hipStream_t stream) {
  const float* enc   = (const float*)d_in[0];
  const float* dec   = (const float*)d_in[1];
  const float* pa    = (const float*)d_in[2];
  const float* Wenc  = (const float*)d_in[3];
  const float* Wdec  = (const float*)d_in[4];
  const float* convw = (const float*)d_in[5];
  const float* Wloc  = (const float*)d_in[6];
  const float* We    = (const float*)d_in[7];
  const float* be    = (const float*)d_in[8];

  float* ctx  = (float*)d_out;                 // [B,E]
  float* attn = (float*)d_out + BATCH * EDIM;  // [B,T]

  float* dec_p = (float*)d_ws;                 // 64 KB
  float* energ = dec_p + BATCH * ADIM;         // 256 KB

  const size_t need = (size_t)(BATCH * ADIM + BATCH * TDIM) * sizeof(float);

  dim3 g1(BATCH, 4);
  dec_proj_kernel<<<g1, 256, 0, stream>>>(dec, Wdec, dec_p);

  dim3 g2(TDIM / 128, BATCH);
  if (ws_size >= need) {
    energies_kernel<<<g2, 256, 0, stream>>>(enc, Wenc, pa, convw, Wloc, We, be,
                                            dec_p, energ);
    dim3 g3(4, BATCH);
    softmax_context_kernel<<<g3, 256, 0, stream>>>(enc, energ, attn, ctx);
  } else {
    energies_kernel<<<g2, 256, 0, stream>>>(enc, Wenc, pa, convw, Wloc, We, be,
                                            dec_p, attn);
    dim3 g3(1, BATCH);
    softmax_context_inplace_kernel<<<g3, 256, 0, stream>>>(enc, attn, ctx);
  }
}